// Round 1
// 1553.953 us; speedup vs baseline: 1.2578x; 1.2578x over previous
//
#include <hip/hip_runtime.h>
#include <math.h>

// Problem constants (R,P,D,H) = (4096,128,128,256); P==D==128.
#define RAYS 4096
#define NPD  128
#define NH   256
#define K2D  256  // 2*NPD, MLP input dim

typedef __attribute__((ext_vector_type(8))) short short8;           // 8 x bf16 (4 VGPRs)
typedef __attribute__((ext_vector_type(4))) float floatx4;          // MFMA C/D frag
typedef __attribute__((ext_vector_type(4))) unsigned short ushort4v;

#define MFMA __builtin_amdgcn_mfma_f32_16x16x32_bf16

__device__ __forceinline__ unsigned short f2bf(float x) {
  union { float f; unsigned int u; } v;
  v.f = x;
  unsigned int u = v.u + 0x7FFFu + ((v.u >> 16) & 1u);  // RNE
  return (unsigned short)(u >> 16);
}

// A/B-operand fragment (8 consecutive bf16 along K) from 8 consecutive global fp32.
__device__ __forceinline__ short8 frag_global(const float* __restrict__ p) {
  floatx4 a = *(const floatx4*)p;
  floatx4 b = *(const floatx4*)(p + 4);
  short8 f;
  f[0] = (short)f2bf(a[0]); f[1] = (short)f2bf(a[1]);
  f[2] = (short)f2bf(a[2]); f[3] = (short)f2bf(a[3]);
  f[4] = (short)f2bf(b[0]); f[5] = (short)f2bf(b[1]);
  f[6] = (short)f2bf(b[2]); f[7] = (short)f2bf(b[3]);
  return f;
}

// Column softmax (over rows i) of score frags held as C-layout stripes:
// sf[ti][tj][rr] at (row = i0+16*ti+4*qq+rr, col = 16*tj+nn).
// red overlays bufB[0..2047]B; trailing barrier protects it from the
// F^T staging (attn_pv) that clobbers bufB right after.
__device__ __forceinline__ void col_softmax(floatx4 (&sf)[2][8], float (*red)[128],
                                            int w, int nn, int qq) {
  float cmax[8];
#pragma unroll
  for (int tj = 0; tj < 8; ++tj) {
    float m = -1e30f;
#pragma unroll
    for (int ti = 0; ti < 2; ++ti)
#pragma unroll
      for (int rr = 0; rr < 4; ++rr) m = fmaxf(m, sf[ti][tj][rr]);
    m = fmaxf(m, __shfl_xor(m, 16, 64));
    m = fmaxf(m, __shfl_xor(m, 32, 64));
    if (qq == 0) red[w][16 * tj + nn] = m;
  }
  __syncthreads();
#pragma unroll
  for (int tj = 0; tj < 8; ++tj) {
    int j = 16 * tj + nn;
    cmax[tj] = fmaxf(fmaxf(red[0][j], red[1][j]), fmaxf(red[2][j], red[3][j]));
  }
  __syncthreads();  // before reusing red for sums
#pragma unroll
  for (int tj = 0; tj < 8; ++tj) {
    float s = 0.f;
#pragma unroll
    for (int ti = 0; ti < 2; ++ti)
#pragma unroll
      for (int rr = 0; rr < 4; ++rr) {
        float e = __expf(sf[ti][tj][rr] - cmax[tj]);
        sf[ti][tj][rr] = e;
        s += e;
      }
    s += __shfl_xor(s, 16, 64);
    s += __shfl_xor(s, 32, 64);
    if (qq == 0) red[w][16 * tj + nn] = s;
  }
  __syncthreads();
#pragma unroll
  for (int tj = 0; tj < 8; ++tj) {
    int j = 16 * tj + nn;
    float inv = 1.0f / (red[0][j] + red[1][j] + red[2][j] + red[3][j]);
#pragma unroll
    for (int ti = 0; ti < 2; ++ti)
#pragma unroll
      for (int rr = 0; rr < 4; ++rr) sf[ti][tj][rr] *= inv;
  }
  __syncthreads();  // all red reads done before bufB is clobbered (overlay)
}

// Store probability stripe (C-layout regs) -> bufA row-major [128][136] bf16, own rows.
__device__ __forceinline__ void store_P(const floatx4 (&sf)[2][8], unsigned short* bufA,
                                        int i0, int nn, int qq) {
#pragma unroll
  for (int ti = 0; ti < 2; ++ti)
#pragma unroll
    for (int rr = 0; rr < 4; ++rr) {
      unsigned short* pr = bufA + (i0 + 16 * ti + 4 * qq + rr) * 136;
#pragma unroll
      for (int tj = 0; tj < 8; ++tj) pr[16 * tj + nn] = f2bf(sf[ti][tj][rr]);
    }
}

// acc[ti][td] += P(stripe, from bufA) @ F(fsrc), F transposed-on-load in 2 j-halves.
__device__ __forceinline__ void attn_pv(const float* __restrict__ fsrc,
                                        unsigned short* bufA, unsigned short* bufB,
                                        floatx4 (&acc)[2][8],
                                        int tid, int i0, int nn, int qq) {
  for (int h = 0; h < 2; ++h) {
    {  // F^T half into bufB: bufB[d][jl], stride 72, packed 4-wide writes
      const int d = tid & 127;
      const int jg = tid >> 7;
#pragma unroll
      for (int jj = 0; jj < 32; jj += 4) {
        int jl = jg * 32 + jj;
        const float* src = fsrc + (64 * h + jl) * NPD + d;
        ushort4v hv;
        hv[0] = f2bf(src[0 * NPD]);
        hv[1] = f2bf(src[1 * NPD]);
        hv[2] = f2bf(src[2 * NPD]);
        hv[3] = f2bf(src[3 * NPD]);
        *(ushort4v*)(bufB + d * 72 + jl) = hv;
      }
    }
    __syncthreads();
    short8 afr[2][2];
#pragma unroll
    for (int ti = 0; ti < 2; ++ti)
#pragma unroll
      for (int kt = 0; kt < 2; ++kt)
        afr[ti][kt] = *(const short8*)(bufA + (i0 + 16 * ti + nn) * 136 + 64 * h + 32 * kt + 8 * qq);
#pragma unroll
    for (int td = 0; td < 8; ++td)
#pragma unroll
      for (int kt = 0; kt < 2; ++kt) {
        short8 bf = *(const short8*)(bufB + (16 * td + nn) * 72 + 32 * kt + 8 * qq);
        acc[0][td] = MFMA(afr[0][kt], bf, acc[0][td], 0, 0, 0);
        acc[1][td] = MFMA(afr[1][kt], bf, acc[1][td], 0, 0, 0);
      }
    __syncthreads();
  }
}

// One-time weight prep: W1T bf16 [NH][K2D] then W2T bf16 [NPD][NH] into ws.
// 65536 + 32768 elements -> 384 blocks x 256 threads, 1 elem/thread.
__global__ __launch_bounds__(256)
void prep_weights(const float* __restrict__ W1, const float* __restrict__ W2,
                  unsigned short* __restrict__ wts) {
  int idx = blockIdx.x * 256 + threadIdx.x;
  if (idx < NH * K2D) {
    int m = idx >> 8;          // 0..255 (hidden)
    int k = idx & 255;         // 0..255 (input)
    wts[idx] = f2bf(W1[k * NH + m]);
  } else {
    int j = idx - NH * K2D;    // 0..32767
    int d = j >> 8;            // 0..127 (output)
    int m = j & 255;           // 0..255 (hidden)
    wts[NH * K2D + j] = f2bf(W2[m * NPD + d]);
  }
}

__global__ __launch_bounds__(256, 3)
void feature_fusion_kernel(const float* __restrict__ semantic,
                           const float* __restrict__ depth,
                           const float* __restrict__ rgb,
                           const float* __restrict__ b1,
                           const float* __restrict__ b2,
                           const unsigned short* __restrict__ wts,
                           float* __restrict__ out) {
  const int r    = blockIdx.x;
  const int tid  = threadIdx.x;
  const int lane = tid & 63;
  const int w    = tid >> 6;   // wave 0..3
  const int nn   = lane & 15;  // A-row / B-col / C-col within tile
  const int qq   = lane >> 4;  // quad 0..3
  const int i0   = 32 * w;     // this wave's stripe base row

  const size_t rbase = (size_t)r * (NPD * NPD);
  const float* sem  = semantic + rbase;
  const float* dep  = depth + rbase;
  const float* rgbp = rgb + rbase;

  // LDS: exactly 53248 B = 160 KiB / 3  -> 3 blocks/CU.
  __shared__ __align__(16) unsigned short bufA[128 * 136];  // 34816 B
  __shared__ __align__(16) unsigned short bufB[128 * 72];   // 18432 B
  // Overlays into bufB (live only while bufB's F^T/h uses are dead):
  float (*s_red)[128] = (float (*)[128])bufB;      // bytes 0..2047
  float* s_invn       = (float*)&bufB[1024];       // bytes 2048..2559

  // ---- phase 1: rgb -> bufA row-major bf16 (+ row norms); depth A-frags ----
  {
    const int p  = tid >> 1;
    const int c0 = (tid & 1) * 64;
    const float* src = rgbp + p * NPD + c0;
    unsigned short* dst = bufA + p * 136 + c0;
    float ss = 0.f;
#pragma unroll
    for (int c = 0; c < 64; c += 4) {
      floatx4 v = *(const floatx4*)(src + c);
      ss += v[0] * v[0] + v[1] * v[1] + v[2] * v[2] + v[3] * v[3];
      ushort4v hv;
      hv[0] = f2bf(v[0]); hv[1] = f2bf(v[1]); hv[2] = f2bf(v[2]); hv[3] = f2bf(v[3]);
      *(ushort4v*)(dst + c) = hv;
    }
    ss += __shfl_xor(ss, 1, 64);
    if ((tid & 1) == 0) s_invn[p] = 1.0f / sqrtf(ss);
  }

  short8 dfrag[2][4];  // depth stripe A-operand frags, reused by BOTH attentions
#pragma unroll
  for (int ti = 0; ti < 2; ++ti)
#pragma unroll
    for (int kt = 0; kt < 4; ++kt)
      dfrag[ti][kt] = frag_global(dep + (i0 + 16 * ti + nn) * NPD + 32 * kt + 8 * qq);

  __syncthreads();

  // ---- phase 2: S1[i,j] = <depth_i, rgb_j> / ||rgb_i|| ----
  floatx4 sf[2][8];
#pragma unroll
  for (int ti = 0; ti < 2; ++ti)
#pragma unroll
    for (int tj = 0; tj < 8; ++tj) sf[ti][tj] = (floatx4){0.f, 0.f, 0.f, 0.f};
#pragma unroll
  for (int tj = 0; tj < 8; ++tj)
#pragma unroll
    for (int kt = 0; kt < 4; ++kt) {
      short8 bf = *(const short8*)(bufA + (16 * tj + nn) * 136 + 32 * kt + 8 * qq);
      sf[0][tj] = MFMA(dfrag[0][kt], bf, sf[0][tj], 0, 0, 0);
      sf[1][tj] = MFMA(dfrag[1][kt], bf, sf[1][tj], 0, 0, 0);
    }
  {
    float rin[2][4];
#pragma unroll
    for (int ti = 0; ti < 2; ++ti)
#pragma unroll
      for (int rr = 0; rr < 4; ++rr) rin[ti][rr] = s_invn[i0 + 16 * ti + 4 * qq + rr];
#pragma unroll
    for (int ti = 0; ti < 2; ++ti)
#pragma unroll
      for (int tj = 0; tj < 8; ++tj)
#pragma unroll
        for (int rr = 0; rr < 4; ++rr) sf[ti][tj][rr] *= rin[ti][rr];
  }

  col_softmax(sf, s_red, w, nn, qq);   // P1 (column-normalized over i)
  store_P(sf, bufA, i0, nn, qq);       // P1 -> bufA (own rows)

  // ---- phase 3: semantic_fused = P1 @ semantic ----
  floatx4 acc[2][8];
#pragma unroll
  for (int ti = 0; ti < 2; ++ti)
#pragma unroll
    for (int td = 0; td < 8; ++td) acc[ti][td] = (floatx4){0.f, 0.f, 0.f, 0.f};
  attn_pv(sem, bufA, bufB, acc, tid, i0, nn, qq);

  // ---- phase 4: SF row norms; SF -> global (output 0); SF -> bufA bf16 ----
  float* outSF = out + rbase;
#pragma unroll
  for (int ti = 0; ti < 2; ++ti)
#pragma unroll
    for (int rr = 0; rr < 4; ++rr) {
      const int row = i0 + 16 * ti + 4 * qq + rr;
      float ss = 0.f;
#pragma unroll
      for (int td = 0; td < 8; ++td) { float v = acc[ti][td][rr]; ss += v * v; }
      ss += __shfl_xor(ss, 1, 64);
      ss += __shfl_xor(ss, 2, 64);
      ss += __shfl_xor(ss, 4, 64);
      ss += __shfl_xor(ss, 8, 64);
      if (nn == 0) s_invn[row] = 1.0f / sqrtf(ss);
      unsigned short* pr = bufA + row * 136;
#pragma unroll
      for (int td = 0; td < 8; ++td) {
        float v = acc[ti][td][rr];
        outSF[row * NPD + 16 * td + nn] = v;
        pr[16 * td + nn] = f2bf(v);
      }
    }
  __syncthreads();

  // ---- phase 5: S2[i,j] = <depth_i, SF_j> / ||SF_i|| ----
#pragma unroll
  for (int ti = 0; ti < 2; ++ti)
#pragma unroll
    for (int tj = 0; tj < 8; ++tj) sf[ti][tj] = (floatx4){0.f, 0.f, 0.f, 0.f};
#pragma unroll
  for (int tj = 0; tj < 8; ++tj)
#pragma unroll
    for (int kt = 0; kt < 4; ++kt) {
      short8 bf = *(const short8*)(bufA + (16 * tj + nn) * 136 + 32 * kt + 8 * qq);
      sf[0][tj] = MFMA(dfrag[0][kt], bf, sf[0][tj], 0, 0, 0);
      sf[1][tj] = MFMA(dfrag[1][kt], bf, sf[1][tj], 0, 0, 0);
    }
  {
    float rin[2][4];
#pragma unroll
    for (int ti = 0; ti < 2; ++ti)
#pragma unroll
      for (int rr = 0; rr < 4; ++rr) rin[ti][rr] = s_invn[i0 + 16 * ti + 4 * qq + rr];
#pragma unroll
    for (int ti = 0; ti < 2; ++ti)
#pragma unroll
      for (int tj = 0; tj < 8; ++tj)
#pragma unroll
        for (int rr = 0; rr < 4; ++rr) sf[ti][tj][rr] *= rin[ti][rr];
  }

  col_softmax(sf, s_red, w, nn, qq);   // P2
  store_P(sf, bufA, i0, nn, qq);       // P2 -> bufA

  // ---- phase 6: x = P2 @ rgb ----
#pragma unroll
  for (int ti = 0; ti < 2; ++ti)
#pragma unroll
    for (int td = 0; td < 8; ++td) acc[ti][td] = (floatx4){0.f, 0.f, 0.f, 0.f};
  attn_pv(rgbp, bufA, bufB, acc, tid, i0, nn, qq);

  // ---- phase 7: xc = [x | rgb] as A-operand fragments in registers ----
#pragma unroll
  for (int ti = 0; ti < 2; ++ti)
#pragma unroll
    for (int rr = 0; rr < 4; ++rr) {
      unsigned short* pr = bufA + (i0 + 16 * ti + 4 * qq + rr) * 136;
#pragma unroll
      for (int td = 0; td < 8; ++td) pr[16 * td + nn] = f2bf(acc[ti][td][rr]);
    }
  __syncthreads();
  short8 xc[2][8];
#pragma unroll
  for (int ti = 0; ti < 2; ++ti)
#pragma unroll
    for (int kt = 0; kt < 4; ++kt)
      xc[ti][kt] = *(const short8*)(bufA + (i0 + 16 * ti + nn) * 136 + 32 * kt + 8 * qq);
#pragma unroll
  for (int ti = 0; ti < 2; ++ti)
#pragma unroll
    for (int kt = 0; kt < 4; ++kt)
      xc[ti][4 + kt] = frag_global(rgbp + (i0 + 16 * ti + nn) * NPD + 32 * kt + 8 * qq);
  __syncthreads();

  // ---- phase 8: MLP, 4 hidden chunks of 64: out = relu(xc@W1+b1)@W2 + b2 ----
  // Weights come pre-transposed in bf16 from global (L2-resident):
  //   w1t[m][k] m<256,k<256 ; w2t[d][m] d<128,m<256.
  // h lives in bufB at each wave's OWN 32 rows -> no barriers needed:
  // per-wave LDS ops complete in order, and bufB's last cross-wave use
  // ended at attn_pv's final __syncthreads.
  const unsigned short* w1t = wts;             // [NH][K2D]
  const unsigned short* w2t = wts + NH * K2D;  // [NPD][NH]

  floatx4 oacc[2][8];
#pragma unroll
  for (int ti = 0; ti < 2; ++ti)
#pragma unroll
    for (int td = 0; td < 8; ++td) oacc[ti][td] = (floatx4){0.f, 0.f, 0.f, 0.f};

  for (int mt = 0; mt < 4; ++mt) {
    const int m0 = 64 * mt;
    floatx4 hacc[2][4];
#pragma unroll
    for (int ti = 0; ti < 2; ++ti)
#pragma unroll
      for (int tm = 0; tm < 4; ++tm) hacc[ti][tm] = (floatx4){0.f, 0.f, 0.f, 0.f};
#pragma unroll
    for (int tm = 0; tm < 4; ++tm) {
      const unsigned short* wrow = w1t + (m0 + 16 * tm + nn) * K2D;
#pragma unroll
      for (int kt = 0; kt < 8; ++kt) {
        short8 bf = *(const short8*)(wrow + 32 * kt + 8 * qq);
        hacc[0][tm] = MFMA(xc[0][kt], bf, hacc[0][tm], 0, 0, 0);
        hacc[1][tm] = MFMA(xc[1][kt], bf, hacc[1][tm], 0, 0, 0);
      }
    }
    // h (relu + b1) -> bufB stride 72, own rows only
    float bb[4];
#pragma unroll
    for (int tm = 0; tm < 4; ++tm) bb[tm] = b1[m0 + 16 * tm + nn];
#pragma unroll
    for (int ti = 0; ti < 2; ++ti)
#pragma unroll
      for (int rr = 0; rr < 4; ++rr) {
        unsigned short* pr = bufB + (i0 + 16 * ti + 4 * qq + rr) * 72;
#pragma unroll
        for (int tm = 0; tm < 4; ++tm) {
          float v = hacc[ti][tm][rr] + bb[tm];
          pr[16 * tm + nn] = f2bf(fmaxf(v, 0.f));
        }
      }
#pragma unroll
    for (int kt = 0; kt < 2; ++kt) {
      short8 a0 = *(const short8*)(bufB + (i0 + nn) * 72 + 32 * kt + 8 * qq);
      short8 a1 = *(const short8*)(bufB + (i0 + 16 + nn) * 72 + 32 * kt + 8 * qq);
#pragma unroll
      for (int td = 0; td < 8; ++td) {
        short8 bf = *(const short8*)(w2t + (16 * td + nn) * NH + m0 + 32 * kt + 8 * qq);
        oacc[0][td] = MFMA(a0, bf, oacc[0][td], 0, 0, 0);
        oacc[1][td] = MFMA(a1, bf, oacc[1][td], 0, 0, 0);
      }
    }
  }

  // ---- phase 9: out (+b2) -> global (output 1) ----
  float* outO = out + (size_t)RAYS * NPD * NPD + rbase;
  float b2v[8];
#pragma unroll
  for (int td = 0; td < 8; ++td) b2v[td] = b2[16 * td + nn];
#pragma unroll
  for (int ti = 0; ti < 2; ++ti)
#pragma unroll
    for (int rr = 0; rr < 4; ++rr) {
      const int row = i0 + 16 * ti + 4 * qq + rr;
#pragma unroll
      for (int td = 0; td < 8; ++td)
        outO[row * NPD + 16 * td + nn] = oacc[ti][td][rr] + b2v[td];
    }
}

extern "C" void kernel_launch(void* const* d_in, const int* in_sizes, int n_in,
                              void* d_out, int out_size, void* d_ws, size_t ws_size,
                              hipStream_t stream) {
  const float* semantic = (const float*)d_in[0];
  const float* depth    = (const float*)d_in[1];
  const float* rgb      = (const float*)d_in[2];
  const float* W1       = (const float*)d_in[3];
  const float* b1       = (const float*)d_in[4];
  const float* W2       = (const float*)d_in[5];
  const float* b2       = (const float*)d_in[6];
  float* out = (float*)d_out;
  unsigned short* wts = (unsigned short*)d_ws;  // needs 196608 B

  // One-time (per launch) bf16 transpose of W1/W2 into workspace.
  prep_weights<<<dim3((NH * K2D + NPD * NH) / 256), dim3(256), 0, stream>>>(W1, W2, wts);
  feature_fusion_kernel<<<dim3(RAYS), dim3(256), 0, stream>>>(
      semantic, depth, rgb, b1, b2, wts, out);
}